// Round 3
// baseline (1151.427 us; speedup 1.0000x reference)
//
#include <hip/hip_runtime.h>
#include <math.h>

// x: (8, 4096, 3*1024) fp32. First-order linear recurrence reformulation:
//   f_t = 1/(1+e^{zi}) ; kv_t = tanh(zx)*(1-f_t) ; a_t = a_{t-1}*f_t
//   y_t = f_t*y_{t-1} + kv_t * a_t/(a_t+eps) ; out = tanh(y_t)*sigmoid(zo)
// Single-kernel chunked scan, two decoupled-lookback chains (A then Y),
// ticket-ordered so resident blocks always hold lowest chunk indices.
#define BATCH 8
#define TLEN  4096
#define DH    1024
#define ROW   3072
#define EPS   1e-4f
#define CHUNK 16
#define NCH   (TLEN / CHUNK)   // 256 chunks per (b)-chain
#define NBLK  (BATCH * NCH)    // 2048 blocks

__device__ __forceinline__ float frcp(float v){ return __builtin_amdgcn_rcpf(v); }
// 1 - sigmoid(z) = 1/(1+e^z)
__device__ __forceinline__ float sigm_neg(float z){ return frcp(1.0f + __expf(z)); }
__device__ __forceinline__ float ftanh(float v){ return 1.0f - 2.0f*frcp(__expf(2.0f*v)+1.0f); }
__device__ __forceinline__ float fsig(float z){ return frcp(1.0f + __expf(-z)); }

// agent-scope (cross-XCD) data access: write-through stores / L2-bypassing loads
__device__ __forceinline__ float gload(const float* p){
    return __hip_atomic_load(p, __ATOMIC_RELAXED, __HIP_MEMORY_SCOPE_AGENT);
}
__device__ __forceinline__ void gstore(float* p, float v){
    __hip_atomic_store(p, v, __ATOMIC_RELAXED, __HIP_MEMORY_SCOPE_AGENT);
}

__global__ __launch_bounds__(256, 2) void glru_scan(
        const float* __restrict__ x, float* __restrict__ out, int* ws)
{
    int* counter = ws;                       // [0]
    int* flagA   = ws + 256;                 // NBLK ints
    int* flagY   = flagA + NBLK;             // NBLK ints
    float* Aagg  = (float*)(ws + 16384);     // 64 KB offset; NBLK*DH floats each
    float* Aincl = Aagg  + (size_t)NBLK * DH;
    float* Qagg  = Aincl + (size_t)NBLK * DH;
    float* Yincl = Qagg  + (size_t)NBLK * DH;

    __shared__ int s_ticket;
    __shared__ int s_flag;
    const int tid = threadIdx.x;
    if (tid == 0)
        s_ticket = __hip_atomic_fetch_add(counter, 1, __ATOMIC_RELAXED,
                                          __HIP_MEMORY_SCOPE_AGENT);
    __syncthreads();
    const int v   = s_ticket;
    const int b   = v & 7;        // chain id — v increasing => c nondecreasing per chain
    const int c   = v >> 3;       // chunk index within chain
    const int idx = b * NCH + c;  // buffer index; chain predecessor is idx-1
    const int d   = 4 * tid;

    const float* xp = x + (size_t)(b * TLEN + c * CHUNK) * ROW + d;

    float4 fr[CHUNK];   // f_t, later overwritten with F_t (inclusive local cumprod)
    float4 kv[CHUNK];   // kv_t, later overwritten with y_local_t

    // ---- phase 1: read zx/zi, pointwise gates, local forget-product ----
    float4 A = make_float4(1.f, 1.f, 1.f, 1.f);
    #pragma unroll
    for (int t = 0; t < CHUNK; ++t) {
        const float* row = xp + (size_t)t * ROW;
        float4 zx = *(const float4*)(row);
        float4 zi = *(const float4*)(row + DH);
        float4 f, k;
#define PW(C) { f.C = sigm_neg(zi.C); k.C = ftanh(zx.C) * (1.0f - f.C); A.C *= f.C; }
        PW(x) PW(y) PW(z) PW(w)
#undef PW
        fr[t] = f; kv[t] = k;
    }

    // ---- publish A aggregate, then lookback for incoming cumprod a_in ----
    {
        size_t o = (size_t)idx * DH + d;
        gstore(Aagg + o + 0, A.x); gstore(Aagg + o + 1, A.y);
        gstore(Aagg + o + 2, A.z); gstore(Aagg + o + 3, A.w);
    }
    __syncthreads();   // drains vmcnt before barrier => data globally issued
    if (c > 0 && tid == 0)
        __hip_atomic_store(flagA + idx, 1, __ATOMIC_RELEASE, __HIP_MEMORY_SCOPE_AGENT);

    float4 ain = make_float4(1.f, 1.f, 1.f, 1.f);
    if (c > 0) {
        int j = idx - 1, jc = c - 1;
        while (jc >= 0) {
            if (tid == 0) {
                int fv;
                do {
                    fv = __hip_atomic_load(flagA + j, __ATOMIC_ACQUIRE,
                                           __HIP_MEMORY_SCOPE_AGENT);
                    if (!fv) __builtin_amdgcn_s_sleep(1);
                } while (!fv);
                s_flag = fv;
            }
            __syncthreads();
            const int fv = s_flag;
            const float* src = (fv == 2 ? Aincl : Aagg) + (size_t)j * DH + d;
            ain.x *= gload(src + 0); ain.y *= gload(src + 1);
            ain.z *= gload(src + 2); ain.w *= gload(src + 3);
            __syncthreads();        // protect s_flag before next hop
            if (fv == 2) break;
            --j; --jc;
        }
    }
    {   // publish inclusive A prefix (shortcut for successors)
        size_t o = (size_t)idx * DH + d;
        gstore(Aincl + o + 0, ain.x * A.x); gstore(Aincl + o + 1, ain.y * A.y);
        gstore(Aincl + o + 2, ain.z * A.z); gstore(Aincl + o + 3, ain.w * A.w);
    }
    __syncthreads();
    if (tid == 0)
        __hip_atomic_store(flagA + idx, 2, __ATOMIC_RELEASE, __HIP_MEMORY_SCOPE_AGENT);

    // ---- phase 3: local recurrence with known a_in (y_in = 0) ----
    float4 a = ain, y = make_float4(0.f, 0.f, 0.f, 0.f);
    float4 F = make_float4(1.f, 1.f, 1.f, 1.f);
    #pragma unroll
    for (int t = 0; t < CHUNK; ++t) {
        float4 f = fr[t], k = kv[t];
#define ST(C) { a.C *= f.C; F.C *= f.C; float r = a.C * frcp(a.C + EPS); \
                y.C = f.C * y.C + k.C * r; }
        ST(x) ST(y) ST(z) ST(w)
#undef ST
        fr[t] = F;   // inclusive local cumprod through t
        kv[t] = y;   // local partial y through t
    }
    // y == Q_c, F == A (recomputed)

    // ---- publish Y aggregate, lookback for incoming y_in ----
    {
        size_t o = (size_t)idx * DH + d;
        gstore(Qagg + o + 0, y.x); gstore(Qagg + o + 1, y.y);
        gstore(Qagg + o + 2, y.z); gstore(Qagg + o + 3, y.w);
    }
    __syncthreads();
    if (c > 0 && tid == 0)
        __hip_atomic_store(flagY + idx, 1, __ATOMIC_RELEASE, __HIP_MEMORY_SCOPE_AGENT);

    float4 yin = make_float4(0.f, 0.f, 0.f, 0.f);
    if (c > 0) {
        float4 carry = make_float4(0.f, 0.f, 0.f, 0.f);
        float4 pf    = make_float4(1.f, 1.f, 1.f, 1.f);
        int j = idx - 1, jc = c - 1;
        while (jc >= 0) {
            if (tid == 0) {
                int fv;
                do {
                    fv = __hip_atomic_load(flagY + j, __ATOMIC_ACQUIRE,
                                           __HIP_MEMORY_SCOPE_AGENT);
                    if (!fv) __builtin_amdgcn_s_sleep(1);
                } while (!fv);
                s_flag = fv;
            }
            __syncthreads();
            const int fv = s_flag;
            const size_t o = (size_t)j * DH + d;
            if (fv == 2) {
                carry.x += pf.x * gload(Yincl + o + 0);
                carry.y += pf.y * gload(Yincl + o + 1);
                carry.z += pf.z * gload(Yincl + o + 2);
                carry.w += pf.w * gload(Yincl + o + 3);
            } else {
                carry.x += pf.x * gload(Qagg + o + 0);
                carry.y += pf.y * gload(Qagg + o + 1);
                carry.z += pf.z * gload(Qagg + o + 2);
                carry.w += pf.w * gload(Qagg + o + 3);
                pf.x *= gload(Aagg + o + 0); pf.y *= gload(Aagg + o + 1);
                pf.z *= gload(Aagg + o + 2); pf.w *= gload(Aagg + o + 3);
            }
            __syncthreads();
            if (fv == 2) break;
            --j; --jc;
        }
        yin = carry;
    }
    {   // publish inclusive Y prefix
        size_t o = (size_t)idx * DH + d;
        gstore(Yincl + o + 0, A.x * yin.x + y.x);
        gstore(Yincl + o + 1, A.y * yin.y + y.y);
        gstore(Yincl + o + 2, A.z * yin.z + y.z);
        gstore(Yincl + o + 3, A.w * yin.w + y.w);
    }
    __syncthreads();
    if (tid == 0)
        __hip_atomic_store(flagY + idx, 2, __ATOMIC_RELEASE, __HIP_MEMORY_SCOPE_AGENT);

    // ---- epilogue: y_t = F_t*y_in + y_local_t ; out = tanh(y_t)*sig(zo) ----
    float* op = out + (size_t)(b * TLEN + c * CHUNK) * DH + d;
    #pragma unroll
    for (int t = 0; t < CHUNK; ++t) {
        const float* row = xp + (size_t)t * ROW;
        float4 zo = *(const float4*)(row + 2 * DH);
        float4 Ft = fr[t], yl = kv[t], o4;
#define EP(C) { float yt = Ft.C * yin.C + yl.C; o4.C = ftanh(yt) * fsig(zo.C); }
        EP(x) EP(y) EP(z) EP(w)
#undef EP
        *(float4*)(op + (size_t)t * DH) = o4;
    }
}

extern "C" void kernel_launch(void* const* d_in, const int* in_sizes, int n_in,
                              void* d_out, int out_size, void* d_ws, size_t ws_size,
                              hipStream_t stream) {
    const float* x = (const float*)d_in[0];
    float* out = (float*)d_out;
    int* ws = (int*)d_ws;

    // zero ticket counter + both flag arrays (first 64 KB of workspace)
    hipMemsetAsync(d_ws, 0, 65536, stream);
    glru_scan<<<dim3(NBLK), dim3(256), 0, stream>>>(x, out, ws);
}